// Round 1
// baseline (255.468 us; speedup 1.0000x reference)
//
#include <hip/hip_runtime.h>
#include <hip/hip_bf16.h>
#include <cstdint>

#define BB 2
#define SS 2048
#define DD 1024
#define HH 16
#define DK 64
#define MROWS (BB*SS)        // 4096
#define NQKV  (3*DD)         // 3072

typedef __bf16 bf16x8 __attribute__((ext_vector_type(8)));
typedef float  f32x4  __attribute__((ext_vector_type(4)));

static __device__ __forceinline__ unsigned short f2bf(float f) {
    __bf16 h = (__bf16)f;
    return __builtin_bit_cast(unsigned short, h);
}
static __device__ __forceinline__ float bf2f(unsigned short u) {
    return (float)__builtin_bit_cast(__bf16, u);
}

#define GLOAD16(gsrc, ldst) \
    __builtin_amdgcn_global_load_lds((const __attribute__((address_space(1))) void*)(gsrc), \
                                     (__attribute__((address_space(3))) void*)(ldst), 16, 0, 0)

// ---------------------------------------------------------------- cast x + weights to bf16
__global__ void cast_all(const float* __restrict__ x,  const float* __restrict__ wq,
                         const float* __restrict__ wk, const float* __restrict__ wv,
                         const float* __restrict__ wo,
                         unsigned short* __restrict__ xb, unsigned short* __restrict__ wqkv,
                         unsigned short* __restrict__ wob)
{
    const int NX = MROWS * DD;      // 4194304
    const int NW = DD * DD;         // 1048576
    const int total = (NX + 4 * NW) / 8;
    for (int i = blockIdx.x * blockDim.x + threadIdx.x; i < total; i += gridDim.x * blockDim.x) {
        int base = i * 8;
        const float* src; unsigned short* dst; int off;
        if      (base < NX)          { src = x;  dst = xb;          off = base; }
        else if (base < NX + NW)     { src = wq; dst = wqkv;        off = base - NX; }
        else if (base < NX + 2*NW)   { src = wk; dst = wqkv + NW;   off = base - NX - NW; }
        else if (base < NX + 3*NW)   { src = wv; dst = wqkv + 2*NW; off = base - NX - 2*NW; }
        else                         { src = wo; dst = wob;         off = base - NX - 3*NW; }
        float4 a = *(const float4*)(src + off);
        float4 b = *(const float4*)(src + off + 4);
        union { unsigned short s[8]; uint4 v; } u;
        u.s[0] = f2bf(a.x); u.s[1] = f2bf(a.y); u.s[2] = f2bf(a.z); u.s[3] = f2bf(a.w);
        u.s[4] = f2bf(b.x); u.s[5] = f2bf(b.y); u.s[6] = f2bf(b.z); u.s[7] = f2bf(b.w);
        *(uint4*)(dst + off) = u.v;
    }
}

// ---------------------------------------------------------------- RoPE cos/sin table [2048][32]
__global__ void rope_table(float* __restrict__ tabc, float* __restrict__ tabs)
{
    int i = blockIdx.x * blockDim.x + threadIdx.x;   // 65536 threads
    int s = i >> 5, d = i & 31;
    float inv = exp2f(-(float)d * (13.287712379549449f / 32.f));  // 10000^(-d/32)
    float ang = (float)s * inv;
    tabc[i] = cosf(ang);
    tabs[i] = sinf(ang);
}

// ---------------------------------------------------------------- GEMM  C[M][N] = A[M][K] * B[N][K]^T
// 128x128 tile, BK=64, 4 waves (2x2), 16x16x32 bf16 MFMA, global_load_lds staging.
template<int OUTF32>
__global__ __launch_bounds__(256) void gemm_bt(
    const unsigned short* __restrict__ A, const unsigned short* __restrict__ Bm,
    void* __restrict__ Cout, const float* __restrict__ bias,
    int M, int N, int K)
{
    __shared__ __align__(16) unsigned short sA[128 * 64];
    __shared__ __align__(16) unsigned short sB[128 * 64];
    const int tid = threadIdx.x;
    const int w = tid >> 6, l = tid & 63;
    const int wm = w >> 1, wn = w & 1;
    const int lr = l & 15, lg = l >> 4;
    const int mBase = blockIdx.y * 128, nBase = blockIdx.x * 128;
    const int srow = tid >> 3;           // 0..31
    const int skof = (tid & 7) * 8;      // element offset in K

    f32x4 acc[4][4] = {};

    for (int kt = 0; kt < K; kt += 64) {
        __syncthreads();
        #pragma unroll
        for (int i = 0; i < 4; ++i) {
            const unsigned short* srcA = A + (size_t)(mBase + i*32 + srow) * K + kt + skof;
            GLOAD16(srcA, &sA[i*2048 + w*512]);
            const unsigned short* srcB = Bm + (size_t)(nBase + i*32 + srow) * K + kt + skof;
            GLOAD16(srcB, &sB[i*2048 + w*512]);
        }
        __syncthreads();
        #pragma unroll
        for (int kk = 0; kk < 2; ++kk) {
            bf16x8 af[4], bfv[4];
            #pragma unroll
            for (int mi = 0; mi < 4; ++mi)
                af[mi] = *(const bf16x8*)&sA[(wm*64 + mi*16 + lr)*64 + kk*32 + lg*8];
            #pragma unroll
            for (int ni = 0; ni < 4; ++ni)
                bfv[ni] = *(const bf16x8*)&sB[(wn*64 + ni*16 + lr)*64 + kk*32 + lg*8];
            #pragma unroll
            for (int mi = 0; mi < 4; ++mi)
                #pragma unroll
                for (int ni = 0; ni < 4; ++ni)
                    acc[mi][ni] = __builtin_amdgcn_mfma_f32_16x16x32_bf16(af[mi], bfv[ni], acc[mi][ni], 0, 0, 0);
        }
    }
    #pragma unroll
    for (int mi = 0; mi < 4; ++mi) {
        #pragma unroll
        for (int j = 0; j < 4; ++j) {
            int row = mBase + wm*64 + mi*16 + lg*4 + j;
            #pragma unroll
            for (int ni = 0; ni < 4; ++ni) {
                int col = nBase + wn*64 + ni*16 + lr;
                float v = acc[mi][ni][j];
                if (OUTF32) ((float*)Cout)[(size_t)row * N + col] = v + bias[col];
                else        ((unsigned short*)Cout)[(size_t)row * N + col] = f2bf(v);
            }
        }
    }
}

// ---------------------------------------------------------------- RoPE apply + V transpose
// qkv: [4096][3072] bf16 (Q|K|V). Writes Qb,Kb [4096][1024], Vt [32][64][2048].
__global__ void rope_apply(const unsigned short* __restrict__ qkv,
                           const int* __restrict__ pids,
                           const float* __restrict__ tabc, const float* __restrict__ tabs,
                           unsigned short* __restrict__ Qb, unsigned short* __restrict__ Kb,
                           unsigned short* __restrict__ Vt)
{
    const int NP = MROWS * HH * 32;   // 2M rope pairs each for Q and K
    const int NV = MROWS * DD;        // 4M V elements
    for (int idx = blockIdx.x * blockDim.x + threadIdx.x; idx < 2*NP + NV;
         idx += gridDim.x * blockDim.x) {
        if (idx < 2 * NP) {
            int isK = idx >= NP;
            int i = isK ? idx - NP : idx;
            int r = i >> 9;           // row in [0,4096)
            int p = i & 511;
            int hh = p >> 5, d = p & 31;
            int pos = pids[r];
            float c  = tabc[pos*32 + d];
            float sn = tabs[pos*32 + d];
            size_t base = (size_t)r * NQKV + (isK ? DD : 0) + hh*64 + d;
            float v1 = bf2f(qkv[base]);
            float v2 = bf2f(qkv[base + 32]);
            unsigned short* dst = isK ? Kb : Qb;
            dst[(size_t)r * DD + hh*64 + d]      = f2bf(v1*c - v2*sn);
            dst[(size_t)r * DD + hh*64 + d + 32] = f2bf(v2*c + v1*sn);
        } else {
            int j = idx - 2*NP;
            int r = j >> 10, c = j & 1023;
            int b = r >> 11, s = r & 2047;
            int hh = c >> 6, d = c & 63;
            Vt[(size_t)((b*HH + hh)*64 + d) * SS + s] = qkv[(size_t)r * NQKV + 2*DD + c];
        }
    }
}

// ---------------------------------------------------------------- flash attention fwd (causal)
// grid (32 qtiles, 32 bh). 4 waves x 16 q-rows = 64-row q tile; kv tiles of 64.
__global__ __launch_bounds__(256) void attn_fwd(
    const unsigned short* __restrict__ Qb,   // [4096][1024]
    const unsigned short* __restrict__ Kb,   // [4096][1024]
    const unsigned short* __restrict__ Vt,   // [32][64][2048]
    unsigned short* __restrict__ Ob)         // [4096][1024]
{
    __shared__ __align__(16) unsigned short sK[64 * 64];
    __shared__ __align__(16) unsigned short sV[64 * 64];
    __shared__ __align__(16) unsigned short sP[4][16 * 64];
    const int tid = threadIdx.x;
    const int w = tid >> 6, l = tid & 63;
    const int lr = l & 15, lg = l >> 4;
    const int qt = blockIdx.x;
    const int bh = blockIdx.y;
    const int b = bh >> 4, h = bh & 15;
    const int q0 = qt*64 + w*16;             // wave's first q row within S
    const float scale = 0.125f;              // 1/sqrt(64)
    const int srow = tid >> 3;
    const int skof = (tid & 7) * 8;

    bf16x8 qf[2];
    {
        const unsigned short* qp = Qb + (size_t)(b*SS + q0 + lr) * DD + h*64 + lg*8;
        qf[0] = *(const bf16x8*)qp;
        qf[1] = *(const bf16x8*)(qp + 32);
    }
    f32x4 oacc[4] = {};
    float mrow[4], lsum[4];
    #pragma unroll
    for (int j = 0; j < 4; ++j) { mrow[j] = -3.0e38f; lsum[j] = 0.f; }

    for (int kt = 0; kt <= qt; ++kt) {
        __syncthreads();
        #pragma unroll
        for (int i = 0; i < 2; ++i) {
            const unsigned short* srcK = Kb + (size_t)(b*SS + kt*64 + i*32 + srow) * DD + h*64 + skof;
            GLOAD16(srcK, &sK[i*2048 + w*512]);
            const unsigned short* srcV = Vt + (size_t)(bh*64 + i*32 + srow) * SS + kt*64 + skof;
            GLOAD16(srcV, &sV[i*2048 + w*512]);
        }
        __syncthreads();

        f32x4 sacc[4] = {};
        #pragma unroll
        for (int kk = 0; kk < 2; ++kk) {
            #pragma unroll
            for (int ni = 0; ni < 4; ++ni) {
                bf16x8 kf = *(const bf16x8*)&sK[(ni*16 + lr)*64 + kk*32 + lg*8];
                sacc[ni] = __builtin_amdgcn_mfma_f32_16x16x32_bf16(qf[kk], kf, sacc[ni], 0, 0, 0);
            }
        }
        const bool diag = (kt == qt);
        float mnew[4];
        #pragma unroll
        for (int j = 0; j < 4; ++j) {
            int qrow = q0 + lg*4 + j;
            float mx = -3.0e38f;
            #pragma unroll
            for (int ni = 0; ni < 4; ++ni) {
                float v = sacc[ni][j] * scale;
                if (diag) {
                    int kcol = kt*64 + ni*16 + lr;
                    if (kcol > qrow) v = -1e30f;
                }
                sacc[ni][j] = v;
                mx = fmaxf(mx, v);
            }
            mx = fmaxf(mx, __shfl_xor(mx, 1));
            mx = fmaxf(mx, __shfl_xor(mx, 2));
            mx = fmaxf(mx, __shfl_xor(mx, 4));
            mx = fmaxf(mx, __shfl_xor(mx, 8));
            mnew[j] = fmaxf(mrow[j], mx);
        }
        #pragma unroll
        for (int j = 0; j < 4; ++j) {
            float alpha = __expf(mrow[j] - mnew[j]);
            float rs = 0.f;
            #pragma unroll
            for (int ni = 0; ni < 4; ++ni) {
                float p = __expf(sacc[ni][j] - mnew[j]);
                sacc[ni][j] = p;
                rs += p;
            }
            rs += __shfl_xor(rs, 1);
            rs += __shfl_xor(rs, 2);
            rs += __shfl_xor(rs, 4);
            rs += __shfl_xor(rs, 8);
            lsum[j] = lsum[j]*alpha + rs;
            mrow[j] = mnew[j];
            #pragma unroll
            for (int di = 0; di < 4; ++di) oacc[di][j] *= alpha;
        }
        // P -> LDS (bf16) to re-fragment C-layout -> A-layout
        #pragma unroll
        for (int j = 0; j < 4; ++j)
            #pragma unroll
            for (int ni = 0; ni < 4; ++ni)
                sP[w][(lg*4 + j)*64 + ni*16 + lr] = f2bf(sacc[ni][j]);
        asm volatile("s_waitcnt lgkmcnt(0)" ::: "memory");
        #pragma unroll
        for (int kk = 0; kk < 2; ++kk) {
            bf16x8 pf = *(const bf16x8*)&sP[w][lr*64 + kk*32 + lg*8];
            #pragma unroll
            for (int di = 0; di < 4; ++di) {
                bf16x8 vf = *(const bf16x8*)&sV[(di*16 + lr)*64 + kk*32 + lg*8];
                oacc[di] = __builtin_amdgcn_mfma_f32_16x16x32_bf16(pf, vf, oacc[di], 0, 0, 0);
            }
        }
    }
    #pragma unroll
    for (int j = 0; j < 4; ++j) {
        float inv = 1.f / lsum[j];
        size_t row = (size_t)(b*SS + q0 + lg*4 + j);
        #pragma unroll
        for (int di = 0; di < 4; ++di)
            Ob[row * DD + h*64 + di*16 + lr] = f2bf(oacc[di][j] * inv);
    }
}

// ---------------------------------------------------------------- launch
extern "C" void kernel_launch(void* const* d_in, const int* in_sizes, int n_in,
                              void* d_out, int out_size, void* d_ws, size_t ws_size,
                              hipStream_t stream)
{
    const float* x  = (const float*)d_in[0];
    // d_in[1] = mask (causal tril; implemented analytically)
    const int* pids = (const int*)d_in[2];
    const float* wq = (const float*)d_in[3];
    const float* wk = (const float*)d_in[4];
    const float* wv = (const float*)d_in[5];
    const float* wo = (const float*)d_in[6];
    const float* bo = (const float*)d_in[7];
    float* out = (float*)d_out;

    char* ws = (char*)d_ws;
    unsigned short* xb   = (unsigned short*)(ws);                        // 8 MB
    unsigned short* wqkv = (unsigned short*)(ws + (size_t)( 8u<<20));    // 6 MB
    unsigned short* wob  = (unsigned short*)(ws + (size_t)(14u<<20));    // 2 MB
    unsigned short* qkvp = (unsigned short*)(ws + (size_t)(16u<<20));    // 24 MB
    unsigned short* Qb   = (unsigned short*)(ws + (size_t)(40u<<20));    // 8 MB
    unsigned short* Kb   = (unsigned short*)(ws + (size_t)(48u<<20));    // 8 MB
    unsigned short* Vt   = (unsigned short*)(ws + (size_t)(56u<<20));    // 8 MB
    float* tabc          = (float*)(ws + (size_t)(64u<<20));             // 256 KB
    float* tabs          = (float*)(ws + (size_t)(64u<<20) + (256u<<10));// 256 KB
    unsigned short* Ob   = xb;  // alias: x_bf16 dead after QKV GEMM

    cast_all<<<dim3(4096), dim3(256), 0, stream>>>(x, wq, wk, wv, wo, xb, wqkv, wob);
    rope_table<<<dim3(256), dim3(256), 0, stream>>>(tabc, tabs);
    gemm_bt<0><<<dim3(NQKV/128, MROWS/128), dim3(256), 0, stream>>>(
        xb, wqkv, (void*)qkvp, (const float*)nullptr, MROWS, NQKV, DD);
    rope_apply<<<dim3(8192), dim3(256), 0, stream>>>(qkvp, pids, tabc, tabs, Qb, Kb, Vt);
    attn_fwd<<<dim3(32, 32), dim3(256), 0, stream>>>(Qb, Kb, Vt, Ob);
    gemm_bt<1><<<dim3(DD/128, MROWS/128), dim3(256), 0, stream>>>(
        Ob, wob, (void*)out, bo, MROWS, DD, DD);
}

// Round 2
// 171.793 us; speedup vs baseline: 1.4871x; 1.4871x over previous
//
#include <hip/hip_runtime.h>
#include <hip/hip_bf16.h>
#include <cstdint>

#define BB 2
#define SS 2048
#define DD 1024
#define HH 16
#define DK 64
#define MROWS (BB*SS)        // 4096
#define NQKV  (3*DD)         // 3072

typedef __bf16 bf16x8 __attribute__((ext_vector_type(8)));
typedef float  f32x4  __attribute__((ext_vector_type(4)));

static __device__ __forceinline__ unsigned short f2bf(float f) {
    __bf16 h = (__bf16)f;
    return __builtin_bit_cast(unsigned short, h);
}
static __device__ __forceinline__ float bf2f(unsigned short u) {
    return (float)__builtin_bit_cast(__bf16, u);
}

#define GLOAD16(gsrc, ldst) \
    __builtin_amdgcn_global_load_lds((const __attribute__((address_space(1))) void*)(gsrc), \
                                     (__attribute__((address_space(3))) void*)(ldst), 16, 0, 0)

// ---------------------------------------------------------------- cast x + weights to bf16
__global__ void cast_all(const float* __restrict__ x,  const float* __restrict__ wq,
                         const float* __restrict__ wk, const float* __restrict__ wv,
                         const float* __restrict__ wo,
                         unsigned short* __restrict__ xb, unsigned short* __restrict__ wqkv,
                         unsigned short* __restrict__ wob)
{
    const int NX = MROWS * DD;      // 4194304
    const int NW = DD * DD;         // 1048576
    const int total = (NX + 4 * NW) / 8;
    for (int i = blockIdx.x * blockDim.x + threadIdx.x; i < total; i += gridDim.x * blockDim.x) {
        int base = i * 8;
        const float* src; unsigned short* dst; int off;
        if      (base < NX)          { src = x;  dst = xb;          off = base; }
        else if (base < NX + NW)     { src = wq; dst = wqkv;        off = base - NX; }
        else if (base < NX + 2*NW)   { src = wk; dst = wqkv + NW;   off = base - NX - NW; }
        else if (base < NX + 3*NW)   { src = wv; dst = wqkv + 2*NW; off = base - NX - 2*NW; }
        else                         { src = wo; dst = wob;         off = base - NX - 3*NW; }
        float4 a = *(const float4*)(src + off);
        float4 b = *(const float4*)(src + off + 4);
        union { unsigned short s[8]; uint4 v; } u;
        u.s[0] = f2bf(a.x); u.s[1] = f2bf(a.y); u.s[2] = f2bf(a.z); u.s[3] = f2bf(a.w);
        u.s[4] = f2bf(b.x); u.s[5] = f2bf(b.y); u.s[6] = f2bf(b.z); u.s[7] = f2bf(b.w);
        *(uint4*)(dst + off) = u.v;
    }
}

// ---------------------------------------------------------------- RoPE cos/sin table [2048][32]
__global__ void rope_table(float* __restrict__ tabc, float* __restrict__ tabs)
{
    int i = blockIdx.x * blockDim.x + threadIdx.x;   // 65536 threads
    int s = i >> 5, d = i & 31;
    float inv = exp2f(-(float)d * (13.287712379549449f / 32.f));  // 10000^(-d/32)
    float ang = (float)s * inv;
    tabc[i] = cosf(ang);
    tabs[i] = sinf(ang);
}

// ---------------------------------------------------------------- GEMM  C[M][N] = A[M][K] * B[N][K]^T
// 128x128 tile, BK=64, 4 waves (2x2), 16x16x32 bf16 MFMA, global_load_lds staging.
template<int OUTF32>
__global__ __launch_bounds__(256) void gemm_bt(
    const unsigned short* __restrict__ A, const unsigned short* __restrict__ Bm,
    void* __restrict__ Cout, const float* __restrict__ bias,
    int M, int N, int K)
{
    __shared__ __align__(16) unsigned short sA[128 * 64];
    __shared__ __align__(16) unsigned short sB[128 * 64];
    const int tid = threadIdx.x;
    const int w = tid >> 6, l = tid & 63;
    const int wm = w >> 1, wn = w & 1;
    const int lr = l & 15, lg = l >> 4;
    const int mBase = blockIdx.y * 128, nBase = blockIdx.x * 128;
    const int srow = tid >> 3;           // 0..31
    const int skof = (tid & 7) * 8;      // element offset in K

    f32x4 acc[4][4] = {};

    for (int kt = 0; kt < K; kt += 64) {
        __syncthreads();
        #pragma unroll
        for (int i = 0; i < 4; ++i) {
            const unsigned short* srcA = A + (size_t)(mBase + i*32 + srow) * K + kt + skof;
            GLOAD16(srcA, &sA[i*2048 + w*512]);
            const unsigned short* srcB = Bm + (size_t)(nBase + i*32 + srow) * K + kt + skof;
            GLOAD16(srcB, &sB[i*2048 + w*512]);
        }
        __syncthreads();
        #pragma unroll
        for (int kk = 0; kk < 2; ++kk) {
            bf16x8 af[4], bfv[4];
            #pragma unroll
            for (int mi = 0; mi < 4; ++mi)
                af[mi] = *(const bf16x8*)&sA[(wm*64 + mi*16 + lr)*64 + kk*32 + lg*8];
            #pragma unroll
            for (int ni = 0; ni < 4; ++ni)
                bfv[ni] = *(const bf16x8*)&sB[(wn*64 + ni*16 + lr)*64 + kk*32 + lg*8];
            #pragma unroll
            for (int mi = 0; mi < 4; ++mi)
                #pragma unroll
                for (int ni = 0; ni < 4; ++ni)
                    acc[mi][ni] = __builtin_amdgcn_mfma_f32_16x16x32_bf16(af[mi], bfv[ni], acc[mi][ni], 0, 0, 0);
        }
    }
    #pragma unroll
    for (int mi = 0; mi < 4; ++mi) {
        #pragma unroll
        for (int j = 0; j < 4; ++j) {
            int row = mBase + wm*64 + mi*16 + lg*4 + j;
            #pragma unroll
            for (int ni = 0; ni < 4; ++ni) {
                int col = nBase + wn*64 + ni*16 + lr;
                float v = acc[mi][ni][j];
                if (OUTF32) ((float*)Cout)[(size_t)row * N + col] = v + bias[col];
                else        ((unsigned short*)Cout)[(size_t)row * N + col] = f2bf(v);
            }
        }
    }
}

// ---------------------------------------------------------------- RoPE on Q,K (vectorized; Q pre-scaled by 1/8)
// thread i: cb = i&3 (8-pair chunk), h = (i>>2)&15, isK = (i>>6)&1, r = i>>7
__global__ void rope_qk(const unsigned short* __restrict__ qkv,
                        const int* __restrict__ pids,
                        const float* __restrict__ tabc, const float* __restrict__ tabs,
                        unsigned short* __restrict__ Qb, unsigned short* __restrict__ Kb)
{
    int i = blockIdx.x * blockDim.x + threadIdx.x;   // 524288 threads
    int cb = i & 3;
    int h  = (i >> 2) & 15;
    int isK = (i >> 6) & 1;
    int r  = i >> 7;
    int pos = pids[r];
    int dbase = cb * 8;

    const unsigned short* src = qkv + (size_t)r * NQKV + isK * DD + h * 64 + dbase;
    union { unsigned short u[8]; uint4 v; } a, bq, o1, o2;
    a.v  = *(const uint4*)src;
    bq.v = *(const uint4*)(src + 32);
    float cs[8], sn[8];
    *(float4*)&cs[0] = *(const float4*)(tabc + pos*32 + dbase);
    *(float4*)&cs[4] = *(const float4*)(tabc + pos*32 + dbase + 4);
    *(float4*)&sn[0] = *(const float4*)(tabs + pos*32 + dbase);
    *(float4*)&sn[4] = *(const float4*)(tabs + pos*32 + dbase + 4);
    float scale = isK ? 1.0f : 0.125f;   // fold 1/sqrt(dk) into Q
    #pragma unroll
    for (int j = 0; j < 8; ++j) {
        float v1 = bf2f(a.u[j]), v2 = bf2f(bq.u[j]);
        o1.u[j] = f2bf((v1*cs[j] - v2*sn[j]) * scale);
        o2.u[j] = f2bf((v2*cs[j] + v1*sn[j]) * scale);
    }
    unsigned short* dst = (isK ? Kb : Qb) + (size_t)r * DD + h * 64 + dbase;
    *(uint4*)dst        = o1.v;
    *(uint4*)(dst + 32) = o2.v;
}

// ---------------------------------------------------------------- V transpose via chunk-swizzled LDS tile
// qkv [4096][3072] (V at col 2048) -> Vt [32*64][2048]
__global__ __launch_bounds__(256) void v_transpose(
    const unsigned short* __restrict__ qkv, unsigned short* __restrict__ Vt)
{
    __shared__ __align__(16) unsigned short sT[64 * 64];
    const int bh = blockIdx.y;          // 0..31
    const int st = blockIdx.x;          // 0..31 (s-tile)
    const int b = bh >> 4, h = bh & 15;
    const int tid = threadIdx.x;
    #pragma unroll
    for (int i = 0; i < 2; ++i) {
        int c = tid + i*256;            // chunk 0..511
        int s = c >> 3, cb = c & 7;
        const unsigned short* src = qkv + (size_t)(b*SS + st*64 + s) * NQKV + 2*DD + h*64 + cb*8;
        uint4 v = *(const uint4*)src;
        *(uint4*)&sT[s*64 + ((cb ^ (s >> 3)) * 8)] = v;   // chunk-swizzled store
    }
    __syncthreads();
    #pragma unroll
    for (int i = 0; i < 2; ++i) {
        int c = tid + i*256;
        int d = c >> 3, sb = c & 7;
        union { unsigned short u[8]; uint4 v; } o;
        #pragma unroll
        for (int e = 0; e < 8; ++e) {
            int s = sb*8 + e;
            o.u[e] = sT[s*64 + (((d >> 3) ^ (s >> 3)) * 8) + (d & 7)];
        }
        *(uint4*)(Vt + (size_t)(bh*64 + d) * SS + st*64 + sb*8) = o.v;
    }
}

// ---------------------------------------------------------------- flash attention fwd (causal)
// grid (16 pairs, 32 bh). Block does q-tiles {pair, 31-pair}: 33 kv-steps each (balanced).
// sK/sV: XOR-swizzled via pre-swizzled global source (rule #21); sP swizzled both sides.
__global__ __launch_bounds__(256) void attn_fwd(
    const unsigned short* __restrict__ Qb,   // [4096][1024], pre-scaled
    const unsigned short* __restrict__ Kb,   // [4096][1024]
    const unsigned short* __restrict__ Vt,   // [2048][2048]
    unsigned short* __restrict__ Ob)         // [4096][1024]
{
    __shared__ __align__(16) unsigned short sK[64 * 64];
    __shared__ __align__(16) unsigned short sV[64 * 64];
    __shared__ __align__(16) unsigned short sP[4][16 * 64];
    const int tid = threadIdx.x;
    const int w = tid >> 6, l = tid & 63;
    const int lr = l & 15, lg = l >> 4;
    const int pair = blockIdx.x;             // 0..15
    const int bh = blockIdx.y;
    const int b = bh >> 4, h = bh & 15;
    const int srow = tid >> 3;
    const int skof = (tid & 7) * 8;
    const int sksw = skof ^ ((srow & 7) * 8);   // pre-swizzled staging col (elements)
    const int rdsw = (lr & 7) * 8;              // read-side XOR term

    for (int half = 0; half < 2; ++half) {
        const int qt = half ? (31 - pair) : pair;
        const int q0 = qt*64 + w*16;
        bf16x8 qf[2];
        {
            const unsigned short* qp = Qb + (size_t)(b*SS + q0 + lr) * DD + h*64 + lg*8;
            qf[0] = *(const bf16x8*)qp;
            qf[1] = *(const bf16x8*)(qp + 32);
        }
        f32x4 oacc[4] = {};
        float mrow[4], lsum[4];
        #pragma unroll
        for (int j = 0; j < 4; ++j) { mrow[j] = -3.0e38f; lsum[j] = 0.f; }

        for (int kt = 0; kt <= qt; ++kt) {
            __syncthreads();
            #pragma unroll
            for (int i = 0; i < 2; ++i) {
                const unsigned short* srcK = Kb + (size_t)(b*SS + kt*64 + i*32 + srow) * DD + h*64 + sksw;
                GLOAD16(srcK, &sK[i*2048 + w*512]);
                const unsigned short* srcV = Vt + (size_t)(bh*64 + i*32 + srow) * SS + kt*64 + sksw;
                GLOAD16(srcV, &sV[i*2048 + w*512]);
            }
            __syncthreads();

            f32x4 sacc[4] = {};
            #pragma unroll
            for (int kk = 0; kk < 2; ++kk) {
                #pragma unroll
                for (int ni = 0; ni < 4; ++ni) {
                    bf16x8 kf = *(const bf16x8*)&sK[(ni*16 + lr)*64 + ((kk*32 + lg*8) ^ rdsw)];
                    sacc[ni] = __builtin_amdgcn_mfma_f32_16x16x32_bf16(qf[kk], kf, sacc[ni], 0, 0, 0);
                }
            }
            const bool diag = (kt == qt);
            float mnew[4];
            #pragma unroll
            for (int j = 0; j < 4; ++j) {
                int qrow = q0 + lg*4 + j;
                float mx = -3.0e38f;
                #pragma unroll
                for (int ni = 0; ni < 4; ++ni) {
                    float v = sacc[ni][j];
                    if (diag) {
                        int kcol = kt*64 + ni*16 + lr;
                        if (kcol > qrow) v = -1e30f;
                    }
                    sacc[ni][j] = v;
                    mx = fmaxf(mx, v);
                }
                mx = fmaxf(mx, __shfl_xor(mx, 1));
                mx = fmaxf(mx, __shfl_xor(mx, 2));
                mx = fmaxf(mx, __shfl_xor(mx, 4));
                mx = fmaxf(mx, __shfl_xor(mx, 8));
                mnew[j] = fmaxf(mrow[j], mx);
            }
            #pragma unroll
            for (int j = 0; j < 4; ++j) {
                float alpha = __expf(mrow[j] - mnew[j]);
                float rs = 0.f;
                #pragma unroll
                for (int ni = 0; ni < 4; ++ni) {
                    float p = __expf(sacc[ni][j] - mnew[j]);
                    sacc[ni][j] = p;
                    rs += p;
                }
                rs += __shfl_xor(rs, 1);
                rs += __shfl_xor(rs, 2);
                rs += __shfl_xor(rs, 4);
                rs += __shfl_xor(rs, 8);
                lsum[j] = lsum[j]*alpha + rs;
                mrow[j] = mnew[j];
                #pragma unroll
                for (int di = 0; di < 4; ++di) oacc[di][j] *= alpha;
            }
            // P -> LDS (bf16), swizzled both sides (manual ds ops)
            #pragma unroll
            for (int j = 0; j < 4; ++j) {
                int rp = lg*4 + j;
                #pragma unroll
                for (int ni = 0; ni < 4; ++ni)
                    sP[w][rp*64 + ((ni*16 + lr) ^ ((rp & 7)*8))] = f2bf(sacc[ni][j]);
            }
            asm volatile("s_waitcnt lgkmcnt(0)" ::: "memory");
            __builtin_amdgcn_sched_barrier(0);
            #pragma unroll
            for (int kk = 0; kk < 2; ++kk) {
                bf16x8 pf = *(const bf16x8*)&sP[w][lr*64 + ((kk*32 + lg*8) ^ rdsw)];
                #pragma unroll
                for (int di = 0; di < 4; ++di) {
                    bf16x8 vf = *(const bf16x8*)&sV[(di*16 + lr)*64 + ((kk*32 + lg*8) ^ rdsw)];
                    oacc[di] = __builtin_amdgcn_mfma_f32_16x16x32_bf16(pf, vf, oacc[di], 0, 0, 0);
                }
            }
        }
        #pragma unroll
        for (int j = 0; j < 4; ++j) {
            float inv = 1.f / lsum[j];
            size_t row = (size_t)(b*SS + q0 + lg*4 + j);
            #pragma unroll
            for (int di = 0; di < 4; ++di)
                Ob[row * DD + h*64 + di*16 + lr] = f2bf(oacc[di][j] * inv);
        }
    }
}

// ---------------------------------------------------------------- launch
extern "C" void kernel_launch(void* const* d_in, const int* in_sizes, int n_in,
                              void* d_out, int out_size, void* d_ws, size_t ws_size,
                              hipStream_t stream)
{
    const float* x  = (const float*)d_in[0];
    // d_in[1] = mask (causal tril; implemented analytically)
    const int* pids = (const int*)d_in[2];
    const float* wq = (const float*)d_in[3];
    const float* wk = (const float*)d_in[4];
    const float* wv = (const float*)d_in[5];
    const float* wo = (const float*)d_in[6];
    const float* bo = (const float*)d_in[7];
    float* out = (float*)d_out;

    char* ws = (char*)d_ws;
    unsigned short* xb   = (unsigned short*)(ws);                        // 8 MB
    unsigned short* wqkv = (unsigned short*)(ws + (size_t)( 8u<<20));    // 6 MB
    unsigned short* wob  = (unsigned short*)(ws + (size_t)(14u<<20));    // 2 MB
    unsigned short* qkvp = (unsigned short*)(ws + (size_t)(16u<<20));    // 24 MB
    unsigned short* Qb   = (unsigned short*)(ws + (size_t)(40u<<20));    // 8 MB
    unsigned short* Kb   = (unsigned short*)(ws + (size_t)(48u<<20));    // 8 MB
    unsigned short* Vt   = (unsigned short*)(ws + (size_t)(56u<<20));    // 8 MB
    float* tabc          = (float*)(ws + (size_t)(64u<<20));             // 256 KB
    float* tabs          = (float*)(ws + (size_t)(64u<<20) + (256u<<10));// 256 KB
    unsigned short* Ob   = xb;  // alias: x_bf16 dead after QKV GEMM

    cast_all<<<dim3(4096), dim3(256), 0, stream>>>(x, wq, wk, wv, wo, xb, wqkv, wob);
    rope_table<<<dim3(256), dim3(256), 0, stream>>>(tabc, tabs);
    gemm_bt<0><<<dim3(NQKV/128, MROWS/128), dim3(256), 0, stream>>>(
        xb, wqkv, (void*)qkvp, (const float*)nullptr, MROWS, NQKV, DD);
    rope_qk<<<dim3(2048), dim3(256), 0, stream>>>(qkvp, pids, tabc, tabs, Qb, Kb);
    v_transpose<<<dim3(32, 32), dim3(256), 0, stream>>>(qkvp, Vt);
    attn_fwd<<<dim3(16, 32), dim3(256), 0, stream>>>(Qb, Kb, Vt, Ob);
    gemm_bt<1><<<dim3(DD/128, MROWS/128), dim3(256), 0, stream>>>(
        Ob, wob, (void*)out, bo, MROWS, DD, DD);
}

// Round 4
// 170.972 us; speedup vs baseline: 1.4942x; 1.0048x over previous
//
#include <hip/hip_runtime.h>
#include <hip/hip_bf16.h>
#include <cstdint>

#define BB 2
#define SS 2048
#define DD 1024
#define HH 16
#define DK 64
#define MROWS (BB*SS)        // 4096
#define NQKV  (3*DD)         // 3072

typedef __bf16 bf16x8 __attribute__((ext_vector_type(8)));
typedef float  f32x4  __attribute__((ext_vector_type(4)));

static __device__ __forceinline__ unsigned short f2bf(float f) {
    __bf16 h = (__bf16)f;
    return __builtin_bit_cast(unsigned short, h);
}
static __device__ __forceinline__ float bf2f(unsigned short u) {
    return (float)__builtin_bit_cast(__bf16, u);
}

#define GLOAD16(gsrc, ldst) \
    __builtin_amdgcn_global_load_lds((const __attribute__((address_space(1))) void*)(gsrc), \
                                     (__attribute__((address_space(3))) void*)(ldst), 16, 0, 0)

// ---------------------------------------------------------------- cast x + weights to bf16
__global__ void cast_all(const float* __restrict__ x,  const float* __restrict__ wq,
                         const float* __restrict__ wk, const float* __restrict__ wv,
                         const float* __restrict__ wo,
                         unsigned short* __restrict__ xb, unsigned short* __restrict__ wqkv,
                         unsigned short* __restrict__ wob)
{
    const int NX = MROWS * DD;      // 4194304
    const int NW = DD * DD;         // 1048576
    const int total = (NX + 4 * NW) / 8;
    for (int i = blockIdx.x * blockDim.x + threadIdx.x; i < total; i += gridDim.x * blockDim.x) {
        int base = i * 8;
        const float* src; unsigned short* dst; int off;
        if      (base < NX)          { src = x;  dst = xb;          off = base; }
        else if (base < NX + NW)     { src = wq; dst = wqkv;        off = base - NX; }
        else if (base < NX + 2*NW)   { src = wk; dst = wqkv + NW;   off = base - NX - NW; }
        else if (base < NX + 3*NW)   { src = wv; dst = wqkv + 2*NW; off = base - NX - 2*NW; }
        else                         { src = wo; dst = wob;         off = base - NX - 3*NW; }
        float4 a = *(const float4*)(src + off);
        float4 b = *(const float4*)(src + off + 4);
        union { unsigned short s[8]; uint4 v; } u;
        u.s[0] = f2bf(a.x); u.s[1] = f2bf(a.y); u.s[2] = f2bf(a.z); u.s[3] = f2bf(a.w);
        u.s[4] = f2bf(b.x); u.s[5] = f2bf(b.y); u.s[6] = f2bf(b.z); u.s[7] = f2bf(b.w);
        *(uint4*)(dst + off) = u.v;
    }
}

// ---------------------------------------------------------------- RoPE cos/sin table [2048][32]
__global__ void rope_table(float* __restrict__ tabc, float* __restrict__ tabs)
{
    int i = blockIdx.x * blockDim.x + threadIdx.x;   // 65536 threads
    int s = i >> 5, d = i & 31;
    float inv = exp2f(-(float)d * (13.287712379549449f / 32.f));  // 10000^(-d/32)
    float ang = (float)s * inv;
    tabc[i] = cosf(ang);
    tabs[i] = sinf(ang);
}

// ---------------------------------------------------------------- GEMM  C[M][N] = A[M][K] * B[N][K]^T
// 128x128 tile, BK=64, 4 waves (2x2), 16x16x32 bf16 MFMA, global_load_lds staging.
template<int OUTF32>
__global__ __launch_bounds__(256) void gemm_bt(
    const unsigned short* __restrict__ A, const unsigned short* __restrict__ Bm,
    void* __restrict__ Cout, const float* __restrict__ bias,
    int M, int N, int K)
{
    __shared__ __align__(16) unsigned short sA[128 * 64];
    __shared__ __align__(16) unsigned short sB[128 * 64];
    const int tid = threadIdx.x;
    const int w = tid >> 6, l = tid & 63;
    const int wm = w >> 1, wn = w & 1;
    const int lr = l & 15, lg = l >> 4;
    const int mBase = blockIdx.y * 128, nBase = blockIdx.x * 128;
    const int srow = tid >> 3;           // 0..31
    const int skof = (tid & 7) * 8;      // element offset in K

    f32x4 acc[4][4] = {};

    for (int kt = 0; kt < K; kt += 64) {
        __syncthreads();
        #pragma unroll
        for (int i = 0; i < 4; ++i) {
            const unsigned short* srcA = A + (size_t)(mBase + i*32 + srow) * K + kt + skof;
            GLOAD16(srcA, &sA[i*2048 + w*512]);
            const unsigned short* srcB = Bm + (size_t)(nBase + i*32 + srow) * K + kt + skof;
            GLOAD16(srcB, &sB[i*2048 + w*512]);
        }
        __syncthreads();
        #pragma unroll
        for (int kk = 0; kk < 2; ++kk) {
            bf16x8 af[4], bfv[4];
            #pragma unroll
            for (int mi = 0; mi < 4; ++mi)
                af[mi] = *(const bf16x8*)&sA[(wm*64 + mi*16 + lr)*64 + kk*32 + lg*8];
            #pragma unroll
            for (int ni = 0; ni < 4; ++ni)
                bfv[ni] = *(const bf16x8*)&sB[(wn*64 + ni*16 + lr)*64 + kk*32 + lg*8];
            #pragma unroll
            for (int mi = 0; mi < 4; ++mi)
                #pragma unroll
                for (int ni = 0; ni < 4; ++ni)
                    acc[mi][ni] = __builtin_amdgcn_mfma_f32_16x16x32_bf16(af[mi], bfv[ni], acc[mi][ni], 0, 0, 0);
        }
    }
    #pragma unroll
    for (int mi = 0; mi < 4; ++mi) {
        #pragma unroll
        for (int j = 0; j < 4; ++j) {
            int row = mBase + wm*64 + mi*16 + lg*4 + j;
            #pragma unroll
            for (int ni = 0; ni < 4; ++ni) {
                int col = nBase + wn*64 + ni*16 + lr;
                float v = acc[mi][ni][j];
                if (OUTF32) ((float*)Cout)[(size_t)row * N + col] = v + bias[col];
                else        ((unsigned short*)Cout)[(size_t)row * N + col] = f2bf(v);
            }
        }
    }
}

// ---------------------------------------------------------------- RoPE on Q,K (vectorized)
// Q pre-scaled by (1/sqrt(dk)) * log2(e) so attention works in the exp2 domain.
__global__ void rope_qk(const unsigned short* __restrict__ qkv,
                        const int* __restrict__ pids,
                        const float* __restrict__ tabc, const float* __restrict__ tabs,
                        unsigned short* __restrict__ Qb, unsigned short* __restrict__ Kb)
{
    int i = blockIdx.x * blockDim.x + threadIdx.x;   // 524288 threads
    int cb = i & 3;
    int h  = (i >> 2) & 15;
    int isK = (i >> 6) & 1;
    int r  = i >> 7;
    int pos = pids[r];
    int dbase = cb * 8;

    const unsigned short* src = qkv + (size_t)r * NQKV + isK * DD + h * 64 + dbase;
    union { unsigned short u[8]; uint4 v; } a, bq, o1, o2;
    a.v  = *(const uint4*)src;
    bq.v = *(const uint4*)(src + 32);
    float cs[8], sn[8];
    *(float4*)&cs[0] = *(const float4*)(tabc + pos*32 + dbase);
    *(float4*)&cs[4] = *(const float4*)(tabc + pos*32 + dbase + 4);
    *(float4*)&sn[0] = *(const float4*)(tabs + pos*32 + dbase);
    *(float4*)&sn[4] = *(const float4*)(tabs + pos*32 + dbase + 4);
    float scale = isK ? 1.0f : 0.1803368801111244f;   // 0.125 * log2(e)
    #pragma unroll
    for (int j = 0; j < 8; ++j) {
        float v1 = bf2f(a.u[j]), v2 = bf2f(bq.u[j]);
        o1.u[j] = f2bf((v1*cs[j] - v2*sn[j]) * scale);
        o2.u[j] = f2bf((v2*cs[j] + v1*sn[j]) * scale);
    }
    unsigned short* dst = (isK ? Kb : Qb) + (size_t)r * DD + h * 64 + dbase;
    *(uint4*)dst        = o1.v;
    *(uint4*)(dst + 32) = o2.v;
}

// ---------------------------------------------------------------- V transpose via chunk-swizzled LDS tile
// qkv [4096][3072] (V at col 2048) -> Vt [32*64][2048]
__global__ __launch_bounds__(256) void v_transpose(
    const unsigned short* __restrict__ qkv, unsigned short* __restrict__ Vt)
{
    __shared__ __align__(16) unsigned short sT[64 * 64];
    const int bh = blockIdx.y;          // 0..31
    const int st = blockIdx.x;          // 0..31 (s-tile)
    const int b = bh >> 4, h = bh & 15;
    const int tid = threadIdx.x;
    #pragma unroll
    for (int i = 0; i < 2; ++i) {
        int c = tid + i*256;            // chunk 0..511
        int s = c >> 3, cb = c & 7;
        const unsigned short* src = qkv + (size_t)(b*SS + st*64 + s) * NQKV + 2*DD + h*64 + cb*8;
        uint4 v = *(const uint4*)src;
        *(uint4*)&sT[s*64 + ((cb ^ (s >> 3)) * 8)] = v;   // chunk-swizzled store
    }
    __syncthreads();
    #pragma unroll
    for (int i = 0; i < 2; ++i) {
        int c = tid + i*256;
        int d = c >> 3, sb = c & 7;
        union { unsigned short u[8]; uint4 v; } o;
        #pragma unroll
        for (int e = 0; e < 8; ++e) {
            int s = sb*8 + e;
            o.u[e] = sT[s*64 + (((d >> 3) ^ (s >> 3)) * 8) + (d & 7)];
        }
        *(uint4*)(Vt + (size_t)(bh*64 + d) * SS + st*64 + sb*8) = o.v;
    }
}

// ---------------------------------------------------------------- flash attention fwd (causal)
// 1D grid of 512, XCD-chunk swizzled so each XCD owns 4 consecutive bh (K/V chunk = 2MB < 4MB L2).
// Block does q-tiles {pair, 31-pair}: 33 kv-steps (balanced). exp2-domain softmax + defer-max (T13).
__global__ __launch_bounds__(256) void attn_fwd(
    const unsigned short* __restrict__ Qb,   // [4096][1024], pre-scaled by 0.125*log2e
    const unsigned short* __restrict__ Kb,   // [4096][1024]
    const unsigned short* __restrict__ Vt,   // [2048][2048]
    unsigned short* __restrict__ Ob)         // [4096][1024]
{
    __shared__ __align__(16) unsigned short sK[64 * 64];
    __shared__ __align__(16) unsigned short sV[64 * 64];
    __shared__ __align__(16) unsigned short sP[4][16 * 64];
    const int tid = threadIdx.x;
    const int w = tid >> 6, l = tid & 63;
    const int lr = l & 15, lg = l >> 4;
    // T1 XCD-chunked swizzle: 512 blocks = 8 XCDs x 64; chunk = 4 bh-groups
    const int swz = (blockIdx.x & 7) * 64 + (blockIdx.x >> 3);
    const int pair = swz & 15;               // 0..15
    const int bh = swz >> 4;                 // 0..31
    const int b = bh >> 4, h = bh & 15;
    const int srow = tid >> 3;
    const int skof = (tid & 7) * 8;
    const int sksw = skof ^ ((srow & 7) * 8);   // pre-swizzled staging col (elements)
    const int rdsw = (lr & 7) * 8;              // read-side XOR term
    const float THR = 12.0f;                    // defer-max threshold (log2 units)

    for (int half = 0; half < 2; ++half) {
        const int qt = half ? (31 - pair) : pair;
        const int q0 = qt*64 + w*16;
        bf16x8 qf[2];
        {
            const unsigned short* qp = Qb + (size_t)(b*SS + q0 + lr) * DD + h*64 + lg*8;
            qf[0] = *(const bf16x8*)qp;
            qf[1] = *(const bf16x8*)(qp + 32);
        }
        f32x4 oacc[4] = {};
        float mrow[4], lsum[4];
        #pragma unroll
        for (int j = 0; j < 4; ++j) { mrow[j] = -3.0e38f; lsum[j] = 0.f; }

        for (int kt = 0; kt <= qt; ++kt) {
            __syncthreads();
            #pragma unroll
            for (int i = 0; i < 2; ++i) {
                const unsigned short* srcK = Kb + (size_t)(b*SS + kt*64 + i*32 + srow) * DD + h*64 + sksw;
                GLOAD16(srcK, &sK[i*2048 + w*512]);
                const unsigned short* srcV = Vt + (size_t)(bh*64 + i*32 + srow) * SS + kt*64 + sksw;
                GLOAD16(srcV, &sV[i*2048 + w*512]);
            }
            __syncthreads();

            f32x4 sacc[4] = {};
            #pragma unroll
            for (int kk = 0; kk < 2; ++kk) {
                #pragma unroll
                for (int ni = 0; ni < 4; ++ni) {
                    bf16x8 kf = *(const bf16x8*)&sK[(ni*16 + lr)*64 + ((kk*32 + lg*8) ^ rdsw)];
                    sacc[ni] = __builtin_amdgcn_mfma_f32_16x16x32_bf16(qf[kk], kf, sacc[ni], 0, 0, 0);
                }
            }
            const bool diag = (kt == qt);
            float tmx[4];
            #pragma unroll
            for (int j = 0; j < 4; ++j) {
                int qrow = q0 + lg*4 + j;
                float mx = -3.0e38f;
                #pragma unroll
                for (int ni = 0; ni < 4; ++ni) {
                    float v = sacc[ni][j];
                    if (diag) {
                        int kcol = kt*64 + ni*16 + lr;
                        if (kcol > qrow) v = -1e30f;
                    }
                    sacc[ni][j] = v;
                    mx = fmaxf(mx, v);
                }
                mx = fmaxf(mx, __shfl_xor(mx, 1));
                mx = fmaxf(mx, __shfl_xor(mx, 2));
                mx = fmaxf(mx, __shfl_xor(mx, 4));
                mx = fmaxf(mx, __shfl_xor(mx, 8));
                tmx[j] = mx;
            }
            // T13 defer-max: rescale only if some row grew by more than THR
            float growth = tmx[0] - mrow[0];
            #pragma unroll
            for (int j = 1; j < 4; ++j) growth = fmaxf(growth, tmx[j] - mrow[j]);
            if (!__all(growth <= THR)) {
                #pragma unroll
                for (int j = 0; j < 4; ++j) {
                    float mnew = fmaxf(mrow[j], tmx[j]);
                    float alpha = exp2f(mrow[j] - mnew);
                    lsum[j] *= alpha;
                    mrow[j] = mnew;
                    #pragma unroll
                    for (int di = 0; di < 4; ++di) oacc[di][j] *= alpha;
                }
            }
            #pragma unroll
            for (int j = 0; j < 4; ++j) {
                float rs = 0.f;
                #pragma unroll
                for (int ni = 0; ni < 4; ++ni) {
                    float p = exp2f(sacc[ni][j] - mrow[j]);
                    sacc[ni][j] = p;
                    rs += p;
                }
                rs += __shfl_xor(rs, 1);
                rs += __shfl_xor(rs, 2);
                rs += __shfl_xor(rs, 4);
                rs += __shfl_xor(rs, 8);
                lsum[j] += rs;
            }
            // P -> LDS (bf16), swizzled both sides (manual ds ops)
            #pragma unroll
            for (int j = 0; j < 4; ++j) {
                int rp = lg*4 + j;
                #pragma unroll
                for (int ni = 0; ni < 4; ++ni)
                    sP[w][rp*64 + ((ni*16 + lr) ^ ((rp & 7)*8))] = f2bf(sacc[ni][j]);
            }
            asm volatile("s_waitcnt lgkmcnt(0)" ::: "memory");
            __builtin_amdgcn_sched_barrier(0);
            #pragma unroll
            for (int kk = 0; kk < 2; ++kk) {
                bf16x8 pf = *(const bf16x8*)&sP[w][lr*64 + ((kk*32 + lg*8) ^ rdsw)];
                #pragma unroll
                for (int di = 0; di < 4; ++di) {
                    bf16x8 vf = *(const bf16x8*)&sV[(di*16 + lr)*64 + ((kk*32 + lg*8) ^ rdsw)];
                    oacc[di] = __builtin_amdgcn_mfma_f32_16x16x32_bf16(pf, vf, oacc[di], 0, 0, 0);
                }
            }
        }
        #pragma unroll
        for (int j = 0; j < 4; ++j) {
            float inv = 1.f / lsum[j];
            size_t row = (size_t)(b*SS + q0 + lg*4 + j);
            #pragma unroll
            for (int di = 0; di < 4; ++di)
                Ob[row * DD + h*64 + di*16 + lr] = f2bf(oacc[di][j] * inv);
        }
    }
}

// ---------------------------------------------------------------- launch
extern "C" void kernel_launch(void* const* d_in, const int* in_sizes, int n_in,
                              void* d_out, int out_size, void* d_ws, size_t ws_size,
                              hipStream_t stream)
{
    const float* x  = (const float*)d_in[0];
    // d_in[1] = mask (causal tril; implemented analytically)
    const int* pids = (const int*)d_in[2];
    const float* wq = (const float*)d_in[3];
    const float* wk = (const float*)d_in[4];
    const float* wv = (const float*)d_in[5];
    const float* wo = (const float*)d_in[6];
    const float* bo = (const float*)d_in[7];
    float* out = (float*)d_out;

    char* ws = (char*)d_ws;
    unsigned short* xb   = (unsigned short*)(ws);                        // 8 MB
    unsigned short* wqkv = (unsigned short*)(ws + (size_t)( 8u<<20));    // 6 MB
    unsigned short* wob  = (unsigned short*)(ws + (size_t)(14u<<20));    // 2 MB
    unsigned short* qkvp = (unsigned short*)(ws + (size_t)(16u<<20));    // 24 MB
    unsigned short* Qb   = (unsigned short*)(ws + (size_t)(40u<<20));    // 8 MB
    unsigned short* Kb   = (unsigned short*)(ws + (size_t)(48u<<20));    // 8 MB
    unsigned short* Vt   = (unsigned short*)(ws + (size_t)(56u<<20));    // 8 MB
    float* tabc          = (float*)(ws + (size_t)(64u<<20));             // 256 KB
    float* tabs          = (float*)(ws + (size_t)(64u<<20) + (256u<<10));// 256 KB
    unsigned short* Ob   = xb;  // alias: x_bf16 dead after QKV GEMM

    cast_all<<<dim3(4096), dim3(256), 0, stream>>>(x, wq, wk, wv, wo, xb, wqkv, wob);
    rope_table<<<dim3(256), dim3(256), 0, stream>>>(tabc, tabs);
    gemm_bt<0><<<dim3(NQKV/128, MROWS/128), dim3(256), 0, stream>>>(
        xb, wqkv, (void*)qkvp, (const float*)nullptr, MROWS, NQKV, DD);
    rope_qk<<<dim3(2048), dim3(256), 0, stream>>>(qkvp, pids, tabc, tabs, Qb, Kb);
    v_transpose<<<dim3(32, 32), dim3(256), 0, stream>>>(qkvp, Vt);
    attn_fwd<<<dim3(512), dim3(256), 0, stream>>>(Qb, Kb, Vt, Ob);
    gemm_bt<1><<<dim3(DD/128, MROWS/128), dim3(256), 0, stream>>>(
        Ob, wob, (void*)out, bo, MROWS, DD, DD);
}